// Round 1
// 1377.719 us; speedup vs baseline: 1.0223x; 1.0223x over previous
//
#include <hip/hip_runtime.h>

// DAHHConv: out = Dn^-1 H De^-1 H^T (x @ theta)
// N=20000, E=10000, in=128, out=64. H DENSE f32 [N,E] = 800MB, streamed twice.
// R3 changes:
//  k2: LDS granule XOR-swizzle (read bank = 16*(sub^(q&1))+eL -> 2-way = free,
//      was 4-way) + 2-deep register prefetch (pva/pvb, ~2 iters = ~900cy ahead).
//  k4: 4x wider K-quantum (512B/row/iter) + named va/vb double-buffer prefetch
//      (old version had dependent load->use per 128B with no pipelining).

#define N_ROWS 20000
#define E_COLS 10000
#define ETILE  128
#define E_PAD2 10112   // 79*128, zero-padded tail
#define OUT_CH 64

typedef __attribute__((ext_vector_type(4))) float f32x4;
typedef __attribute__((ext_vector_type(8))) short s16x8;

__device__ __forceinline__ unsigned short f2bf(float f) {
  unsigned int u = __float_as_uint(f);
  u += 0x7FFFu + ((u >> 16) & 1u);
  return (unsigned short)(u >> 16);
}

// ---------------- kernel 1: xwT[c][n] = (x @ theta)^T, stored bf16 ----------------
__global__ __launch_bounds__(256) void k1_xwt(const float* __restrict__ x,
                                              const float* __restrict__ theta,
                                              unsigned short* __restrict__ xwT) {
  __shared__ float xt[64][129];
  const int n0 = blockIdx.x * 64;
  const int t  = threadIdx.x;
  #pragma unroll
  for (int i = 0; i < 8; ++i) {
    int f  = t + 256 * i;
    int r  = f >> 5;
    int c4 = (f & 31) * 4;
    float4 v = make_float4(0.f, 0.f, 0.f, 0.f);
    if (n0 + r < N_ROWS) v = *(const float4*)&x[(long)(n0 + r) * 128 + c4];
    xt[r][c4] = v.x; xt[r][c4 + 1] = v.y; xt[r][c4 + 2] = v.z; xt[r][c4 + 3] = v.w;
  }
  __syncthreads();
  const int nl = t & 63;
  const int cg = t >> 6;
  const int n  = n0 + nl;
  float acc[16];
  #pragma unroll
  for (int i = 0; i < 16; ++i) acc[i] = 0.f;
  #pragma unroll 4
  for (int k = 0; k < 128; ++k) {
    float xv = xt[nl][k];
    const float* th = theta + k * 64 + cg * 16;
    #pragma unroll
    for (int i = 0; i < 16; ++i) acc[i] += xv * th[i];
  }
  if (n < N_ROWS) {
    #pragma unroll
    for (int i = 0; i < 16; ++i)
      xwT[(long)(cg * 16 + i) * N_ROWS + n] = f2bf(acc[i]);
  }
}

// ---------------- kernel 2: eacc[c][e] += sum_n xwT[c][n]*H[n][e]; de[e] += colsum ----
// grid: 79 e-tiles x 25 K-chunks = 1975 blocks x 256 threads (4 waves).
// LDS tile [32][128] f32, 16B granules XOR-swizzled by row bits 3..4:
//   elem (r,c) stored at col ((c>>2) ^ ((r>>3)<<2))*4 + (c&3).
// Write (row r = sr+8i): granule (t&31)^(i<<2) -> full permutation, conflict-free.
// Read  (row r = 8q+j):  bank = 16*(sub^(q&1)) + eL -> exact 2 lanes/bank (free).
__global__ __launch_bounds__(256) void k2_edge(const float* __restrict__ H,
                                               const unsigned short* __restrict__ xwT,
                                               float* __restrict__ eacc,
                                               float* __restrict__ de) {
  __shared__ float tile[32][ETILE];       // 16KB, swizzled granules
  const int b  = blockIdx.x;
  const int et = b % 79, s = b / 79;
  const int e0 = et * ETILE;
  const int t  = threadIdx.x;
  const int w  = t >> 6;                  // wave id 0..3 -> cols [32w, 32w+32)
  const int l  = t & 63;
  const int q  = l >> 4, eL = l & 15;

  const int sr = t >> 5;                  // staging row 0..7 (+8 per round)
  const int sc = (t & 31) * 4;            // staging col
  const int eg = e0 + sc;                 // kk-invariant guard
  const bool egv = (eg < E_COLS);
  const f32x4 z4 = {0, 0, 0, 0};

  f32x4 acc[2][4];
  #pragma unroll
  for (int sub = 0; sub < 2; ++sub)
    #pragma unroll
    for (int ct = 0; ct < 4; ++ct) acc[sub][ct] = z4;
  float deP[2] = {0.f, 0.f};

  const int c0 = 25 * s, c1 = c0 + 25;    // 625 = 25*25 n-chunks of 32 rows

  // 2-deep prefetch: pva holds chunk kk (even offset), pvb kk+1 (odd offset)
  f32x4 pva[4], pvb[4];
  #pragma unroll
  for (int i = 0; i < 4; ++i) {
    pva[i] = egv ? *(const f32x4*)&H[(long)(c0 * 32 + sr + 8 * i) * E_COLS + eg] : z4;
    pvb[i] = egv ? *(const f32x4*)&H[(long)((c0 + 1) * 32 + sr + 8 * i) * E_COLS + eg] : z4;
  }

  int kk = c0;
#define K2_STEP(PV)                                                                     \
  {                                                                                     \
    _Pragma("unroll")                                                                   \
    for (int i = 0; i < 4; ++i)                                                         \
      *(f32x4*)&tile[sr + 8 * i][(((t & 31) ^ (i << 2)) << 2)] = PV[i];                 \
    __syncthreads();                                                                    \
    if (kk + 2 < c1) {  /* refill 2 iterations ahead */                                 \
      _Pragma("unroll")                                                                 \
      for (int i = 0; i < 4; ++i)                                                       \
        PV[i] = egv ? *(const f32x4*)&H[(long)((kk + 2) * 32 + sr + 8 * i) * E_COLS + eg] : z4; \
    }                                                                                   \
    s16x8 af[4];                                                                        \
    _Pragma("unroll")                                                                   \
    for (int ct = 0; ct < 4; ++ct)                                                      \
      af[ct] = *(const s16x8*)&xwT[(long)(ct * 16 + eL) * N_ROWS + kk * 32 + 8 * q];    \
    _Pragma("unroll")                                                                   \
    for (int sub = 0; sub < 2; ++sub) {                                                 \
      const int ec  = 32 * w + 16 * sub + eL;                                           \
      const int csw = (((ec >> 2) ^ (q << 2)) << 2) | (ec & 3);                         \
      union { s16x8 v8; unsigned short u[8]; } bf;                                      \
      float ds = 0.f;                                                                   \
      _Pragma("unroll")                                                                 \
      for (int j = 0; j < 8; ++j) {                                                     \
        float v = tile[8 * q + j][csw];                                                 \
        ds += v;                                                                        \
        bf.u[j] = f2bf(v);                                                              \
      }                                                                                 \
      deP[sub] += ds;                                                                   \
      _Pragma("unroll")                                                                 \
      for (int ct = 0; ct < 4; ++ct)                                                    \
        acc[sub][ct] = __builtin_amdgcn_mfma_f32_16x16x32_bf16(af[ct], bf.v8, acc[sub][ct], 0, 0, 0); \
    }                                                                                   \
    __syncthreads();                                                                    \
    ++kk;                                                                               \
  }

  #pragma unroll 1
  for (int it = 0; it < 12; ++it) { K2_STEP(pva); K2_STEP(pvb); }
  K2_STEP(pva);                           // 25th (odd count) — pva refilled at kk=c0+22
#undef K2_STEP

  // D layout: row(c) = 4q+r, col(e) = eL
  #pragma unroll
  for (int sub = 0; sub < 2; ++sub)
    #pragma unroll
    for (int ct = 0; ct < 4; ++ct)
      #pragma unroll
      for (int r = 0; r < 4; ++r) {
        int c = ct * 16 + q * 4 + r;
        int e = e0 + 32 * w + 16 * sub + eL;
        atomicAdd(&eacc[(long)c * E_PAD2 + e], acc[sub][ct][r]);
      }
  #pragma unroll
  for (int sub = 0; sub < 2; ++sub) {
    float d = deP[sub];
    d += __shfl_xor(d, 16, 64);
    d += __shfl_xor(d, 32, 64);
    if (l < 16) atomicAdd(&de[e0 + 32 * w + 16 * sub + l], d);
  }
}

// ---------------- kernel 3: edgeT[c][e] = bf16(eacc[c][e]/de[e]); zero pad ----------
__global__ __launch_bounds__(256) void k3_edgefin(const float* __restrict__ eacc,
                                                  const float* __restrict__ de,
                                                  unsigned short* __restrict__ eT) {
  const int e = blockIdx.x * 256 + threadIdx.x;
  const int c = blockIdx.y;
  if (e >= E_PAD2) return;
  float v = 0.f;
  if (e < E_COLS) v = eacc[(long)c * E_PAD2 + e] / de[e];
  eT[(long)c * E_PAD2 + e] = f2bf(v);
}

// ---------------- kernel 4: out[n][c] += sum_e H[n][e]*edgeT[c][e]; dn[n] += rowsum --
// grid: 1250 m-tiles x 4 s-chunks = 5000 blocks of 1 wave.
// Per big-iter: 128 e-cols (512B per row), 16 MFMA; next chunk prefetched into the
// other named register buffer (va/vb) so HBM latency hides under compute.
__global__ __launch_bounds__(64) void k4_node(const float* __restrict__ H,
                                              const unsigned short* __restrict__ eT,
                                              float* __restrict__ outacc,
                                              float* __restrict__ dn) {
  const int b  = blockIdx.x;
  const int mt = b % 1250, s = b / 1250;
  const int n0 = mt * 16;
  const int l  = threadIdx.x;
  const int q  = l >> 4, nL = l & 15;
  f32x4 acc[4] = {{0,0,0,0},{0,0,0,0},{0,0,0,0},{0,0,0,0}};
  float dnP = 0.f;
  const float* __restrict__ Hrow = H + (long)(n0 + nL) * E_COLS;
  const f32x4 z4 = {0, 0, 0, 0};
  const int cb0 = s * 20;
  const int cb1 = (cb0 + 20 < 79) ? (cb0 + 20) : 79;   // s=3 gets 19 chunks

#define K4_LOAD(V, CB)                                                   \
  { _Pragma("unroll")                                                    \
    for (int u = 0; u < 8; ++u) {                                        \
      const int col = (CB) * 128 + (u >> 1) * 32 + q * 8 + (u & 1) * 4;  \
      V[u] = (col < E_COLS) ? *(const f32x4*)(Hrow + col) : z4;          \
    } }

#define K4_CONSUME(V, CB)                                                \
  { _Pragma("unroll")                                                    \
    for (int kc = 0; kc < 4; ++kc) {                                     \
      const int ec = (CB) * 128 + kc * 32 + q * 8;                       \
      union { s16x8 v8; unsigned short u[8]; } af;                       \
      _Pragma("unroll")                                                  \
      for (int j = 0; j < 4; ++j) {                                      \
        float av = V[2 * kc][j], cv = V[2 * kc + 1][j];                  \
        dnP += av + cv;                                                  \
        af.u[j] = f2bf(av); af.u[4 + j] = f2bf(cv);                      \
      }                                                                  \
      _Pragma("unroll")                                                  \
      for (int ct = 0; ct < 4; ++ct) {                                   \
        s16x8 bf = *(const s16x8*)&eT[(long)(ct * 16 + nL) * E_PAD2 + ec]; \
        acc[ct] = __builtin_amdgcn_mfma_f32_16x16x32_bf16(af.v8, bf, acc[ct], 0, 0, 0); \
      }                                                                  \
    } }

  f32x4 va[8], vb[8];
  K4_LOAD(va, cb0);
  int cb = cb0, rem = cb1 - cb0;          // 20 or 19
  while (rem >= 2) {
    K4_LOAD(vb, cb + 1);                  // prefetch next chunk
    K4_CONSUME(va, cb);
    ++cb; --rem;
    if (rem >= 2) { K4_LOAD(va, cb + 1); }
    K4_CONSUME(vb, cb);
    ++cb; --rem;
  }
  if (rem) { K4_CONSUME(va, cb); }        // odd-count tail (s=3)
#undef K4_LOAD
#undef K4_CONSUME

  #pragma unroll
  for (int ct = 0; ct < 4; ++ct)
    #pragma unroll
    for (int r = 0; r < 4; ++r)
      atomicAdd(&outacc[(long)(n0 + q * 4 + r) * OUT_CH + ct * 16 + nL], acc[ct][r]);
  dnP += __shfl_xor(dnP, 16, 64);
  dnP += __shfl_xor(dnP, 32, 64);
  if (l < 16) atomicAdd(&dn[n0 + l], dnP);
}

// ---------------- kernel 5: out /= dn ----------------
__global__ __launch_bounds__(256) void k5_nodefin(float* __restrict__ out,
                                                  const float* __restrict__ dn) {
  const int idx = blockIdx.x * 256 + threadIdx.x;
  out[idx] = out[idx] / dn[idx >> 6];
}

extern "C" void kernel_launch(void* const* d_in, const int* in_sizes, int n_in,
                              void* d_out, int out_size, void* d_ws, size_t ws_size,
                              hipStream_t stream) {
  const float* x     = (const float*)d_in[0];
  const float* H     = (const float*)d_in[1];
  const float* theta = (const float*)d_in[2];
  float* out = (float*)d_out;
  char* ws = (char*)d_ws;

  // workspace layout (256B-aligned offsets), total ~6.56 MB
  const size_t OFF_XWT  = 0;                    // bf16 [64][20000] = 2,560,000
  const size_t OFF_EACC = 2560000;              // f32  [64][10112] = 2,588,672
  const size_t OFF_DE   = OFF_EACC + 2588672;   // f32  [10112]     = 40,448
  const size_t OFF_DN   = OFF_DE + 40448;       // f32  [20000]     = 80,000 -> pad 80,128
  const size_t OFF_ET   = OFF_DN + 80128;       // bf16 [64][10112] = 1,294,336

  unsigned short* xwT  = (unsigned short*)(ws + OFF_XWT);
  float*          eacc = (float*)(ws + OFF_EACC);
  float*          de   = (float*)(ws + OFF_DE);
  float*          dn   = (float*)(ws + OFF_DN);
  unsigned short* eT   = (unsigned short*)(ws + OFF_ET);

  hipMemsetAsync(eacc, 0, 2588672, stream);
  hipMemsetAsync(de,   0, 40448,   stream);
  hipMemsetAsync(dn,   0, 80000,   stream);
  hipMemsetAsync(out,  0, (size_t)out_size * sizeof(float), stream);

  k1_xwt<<<313, 256, 0, stream>>>(x, theta, xwT);
  k2_edge<<<1975, 256, 0, stream>>>(H, xwT, eacc, de);
  k3_edgefin<<<dim3(40, 64), 256, 0, stream>>>(eacc, de, eT);
  k4_node<<<5000, 64, 0, stream>>>(H, eT, out, dn);
  k5_nodefin<<<5000, 256, 0, stream>>>(out, dn);
}